// Round 12
// baseline (916.190 us; speedup 1.0000x reference)
//
#include <hip/hip_runtime.h>
#include <hip/hip_bf16.h>

typedef unsigned short u16;
typedef __bf16 bf16x8 __attribute__((ext_vector_type(8)));
typedef float f32x4 __attribute__((ext_vector_type(4)));

#define E_ 8
#define H_ 2048
#define D_ 2048
#define T_ 2048
#define N2_ 4096

__device__ __forceinline__ u16 f2bf(float f) {
    unsigned u = __builtin_bit_cast(unsigned, f);
    unsigned r = (u + 0x7FFFu + ((u >> 16) & 1u)) >> 16;
    return (u16)r;
}

typedef __attribute__((address_space(1))) const void* gptr_t;
typedef __attribute__((address_space(3))) void* lptr_t;
__device__ __forceinline__ void gload16(const void* g, void* l) {
    __builtin_amdgcn_global_load_lds((gptr_t)g, (lptr_t)l, 16, 0, 0);
}
__device__ __forceinline__ unsigned lds_addr(void* p) {
    return (unsigned)(size_t)(lptr_t)p;
}

// ---------------- conversion / transpose pre-pass (unchanged) --------------

__global__ __launch_bounds__(256) void k_convert_x(const float4* __restrict__ x,
                                                   ushort4* __restrict__ xb) {
    int i = blockIdx.x * 256 + threadIdx.x;
    float4 v = x[i];
    ushort4 o;
    o.x = f2bf(v.x); o.y = f2bf(v.y); o.z = f2bf(v.z); o.w = f2bf(v.w);
    xb[i] = o;
}

// gate_up_w fp32 [E][H][2D] -> wP bf16 [E][4096][H]: transpose + de-interleave
// into 16-col gate/up groups: gate d -> row ((d>>4)<<5)+(d&15), up +16.
__global__ __launch_bounds__(256) void k_tr_gateup(const float* __restrict__ w,
                                                   u16* __restrict__ wP) {
    __shared__ u16 Gs[64 * 73];
    __shared__ u16 Us[64 * 73];
    const int e = blockIdx.z, h0 = blockIdx.x * 64, d0 = blockIdx.y * 64;
    const int tid = threadIdx.x;
    {
        const int hl = tid >> 2;
        const int cseg = (tid & 3) * 32;
        const float* src = w + ((size_t)e * H_ + h0 + hl) * N2_ + 2 * d0 + cseg;
#pragma unroll
        for (int q = 0; q < 8; q++) {
            float4 v = *(const float4*)(src + q * 4);
            int dl = (cseg + q * 4) >> 1;
            Gs[hl * 73 + dl]     = f2bf(v.x);
            Us[hl * 73 + dl]     = f2bf(v.y);
            Gs[hl * 73 + dl + 1] = f2bf(v.z);
            Us[hl * 73 + dl + 1] = f2bf(v.w);
        }
    }
    __syncthreads();
    {
        const int dl = tid >> 2;
        const int hseg = (tid & 3) * 16;
        u16 vg[16] __attribute__((aligned(16)));
        u16 vu[16] __attribute__((aligned(16)));
#pragma unroll
        for (int j = 0; j < 16; j++) {
            vg[j] = Gs[(hseg + j) * 73 + dl];
            vu[j] = Us[(hseg + j) * 73 + dl];
        }
        const int d = d0 + dl;
        const int rg = ((d >> 4) << 5) + (d & 15);
        size_t obg = ((size_t)e * N2_ + rg) * H_ + h0 + hseg;
        size_t obu = obg + (size_t)16 * H_;
        *(uint4*)&wP[obg]     = *(const uint4*)&vg[0];
        *(uint4*)&wP[obg + 8] = *(const uint4*)&vg[8];
        *(uint4*)&wP[obu]     = *(const uint4*)&vu[0];
        *(uint4*)&wP[obu + 8] = *(const uint4*)&vu[8];
    }
}

// down_w fp32 [E][D][H] -> wdT bf16 [E][H][D]
__global__ __launch_bounds__(256) void k_tr_down(const float* __restrict__ w,
                                                 u16* __restrict__ wdT) {
    __shared__ u16 Ts[64 * 73];
    const int e = blockIdx.z, d0 = blockIdx.x * 64, h0 = blockIdx.y * 64;
    const int tid = threadIdx.x;
    {
        const int dl = tid >> 2;
        const int hseg = (tid & 3) * 16;
        const float* src = w + ((size_t)e * D_ + d0 + dl) * H_ + h0 + hseg;
#pragma unroll
        for (int q = 0; q < 4; q++) {
            float4 v = *(const float4*)(src + q * 4);
            int hl = hseg + q * 4;
            Ts[(hl + 0) * 73 + dl] = f2bf(v.x);
            Ts[(hl + 1) * 73 + dl] = f2bf(v.y);
            Ts[(hl + 2) * 73 + dl] = f2bf(v.z);
            Ts[(hl + 3) * 73 + dl] = f2bf(v.w);
        }
    }
    __syncthreads();
    {
        const int hl = tid >> 2;
        const int dseg = (tid & 3) * 16;
        u16 vd[16] __attribute__((aligned(16)));
#pragma unroll
        for (int j = 0; j < 16; j++) vd[j] = Ts[hl * 73 + dseg + j];
        size_t ob = ((size_t)e * H_ + h0 + hl) * D_ + d0 + dseg;
        *(uint4*)&wdT[ob]     = *(const uint4*)&vd[0];
        *(uint4*)&wdT[ob + 8] = *(const uint4*)&vd[8];
    }
}

// ------------- 256x128 / BK=32 / 8-wave / 2-blocks-per-CU GEMM -------------
//
// R9: occupancy restructure (R5 falsifier triggered: lockstep phases at
// 1 block/CU serialize LDS-read-service and MFMA; 43% MfmaUtil plateau).
// New geometry: tile 256x128, BK=32, wave owns 128x32 (acc[8][2]=64 VGPR,
// af[8]+bf[2]=40 -> ~125 total, fits 512/4=128), LDS = 3 bufs x (A 16KB +
// B 8KB) = 72KB -> TWO blocks/CU. The co-resident block's MFMA fills this
// block's read/barrier/vmcnt gaps (m114 overlap; same mechanism as m97).
// Pipeline: tile t reads buf0 while tile t+1 (buf1) and t+2 (buf2) stage in
// flight; ONE barrier per tile; vmcnt(3) keeps t+2's 3 loads in flight
// (never drains to 0). Ledger: at body t's VMW3, queue = {t+1: 3, t+2: 3};
// wait-3 drains t+1's exactly -> next body's reads safe after BAR. Buffer
// rotation by value swap (no dynamic indexing -> no scratch, rule #20).
// LDS rows now 32 u16 = 64B = 4 chunks; swizzle chunk_phys = chunk ^
// ((row>>1)&3) -> a frag read's 16 lanes hit 8 slots = 2-way = free.
// Stage source pre-swizzled: csrc = ((l&3) ^ ((l>>3)&3)) * 8 u16.

#define UNROLL _Pragma("unroll")

#define DSR(dst, vaddr, imm)                                                  \
    asm volatile("ds_read_b128 %0, %1 offset:%2"                              \
                 : "=v"(dst) : "v"(vaddr), "i"(imm));

#define LGKM0 asm volatile("s_waitcnt lgkmcnt(0)" ::: "memory");
#define VMW3  asm volatile("s_waitcnt vmcnt(3)" ::: "memory");
#define SB __builtin_amdgcn_sched_barrier(0);
#define BAR __builtin_amdgcn_s_barrier();

// A tile 256x32: 2 gload16/lane. Ag = tile origin (row t0, this kt's cols).
__device__ __forceinline__ void stA(const u16* Ag, size_t ldg, u16* Asb, unsigned offB,
                                    int wave, int srow, int csrc) {
    u16* d = (u16*)((char*)Asb + offB);
    gload16(Ag + (size_t)(wave * 16 + srow) * ldg + csrc, d + (wave * 16) * 32);
    gload16(Ag + (size_t)(128 + wave * 16 + srow) * ldg + csrc, d + (128 + wave * 16) * 32);
}
// B tile 128x32: 1 gload16/lane.
__device__ __forceinline__ void stB(const u16* Bg, size_t ldg, u16* Bsb, unsigned offB,
                                    int wave, int srow, int csrc) {
    u16* d = (u16*)((char*)Bsb + offB);
    gload16(Bg + (size_t)(wave * 16 + srow) * ldg + csrc, d + (wave * 16) * 32);
}

#define GEMM_SETUP                                                            \
    const int tid = threadIdx.x;                                              \
    const int lane = tid & 63;                                                \
    const int wave = tid >> 6;                                                \
    const int wr = (wave >> 2) * 128;                                         \
    const int wc = (wave & 3) * 32;                                           \
    const int l16 = lane & 15;                                                \
    const int quad = lane >> 4;                                               \
    const int srow = lane >> 2;                                               \
    const int csrc = (((lane & 3) ^ ((lane >> 3) & 3)) * 8);                  \
    const unsigned rswz = (unsigned)((quad ^ ((l16 >> 1) & 3)) * 16);         \
    const unsigned la  = lds_addr(As) + (unsigned)(wr + l16) * 64 + rswz;     \
    const unsigned lbB = lds_addr(Bs) + (unsigned)(wc + l16) * 64 + rswz;     \
    f32x4 acc[8][2];                                                          \
    const f32x4 vzero = {0.f, 0.f, 0.f, 0.f};                                 \
    UNROLL for (int i = 0; i < 8; i++) {                                      \
        acc[i][0] = vzero; acc[i][1] = vzero;                                 \
    }                                                                         \
    bf16x8 af[8], bf[2];

#define MFMA16                                                                \
    UNROLL for (int i = 0; i < 8; i++)                                        \
    UNROLL for (int j = 0; j < 2; j++)                                        \
        acc[i][j] = __builtin_amdgcn_mfma_f32_16x16x32_bf16(                  \
            af[i], bf[j], acc[i][j], 0, 0, 0);

// body: reads(buf0) | stage tile s(buf2) | lgkm0 | 16 MFMA | vmcnt(3) | BAR
#define KBODY(AGX, BGX, LDG, NTK)                                             \
    {                                                                         \
        const unsigned ra = la + aby0;                                        \
        const unsigned rb = lbB + bby0;                                       \
        DSR(af[0], ra, 0)    DSR(af[1], ra, 1024)                             \
        DSR(af[2], ra, 2048) DSR(af[3], ra, 3072)                             \
        DSR(af[4], ra, 4096) DSR(af[5], ra, 5120)                             \
        DSR(af[6], ra, 6144) DSR(af[7], ra, 7168)                             \
        DSR(bf[0], rb, 0)    DSR(bf[1], rb, 1024)                             \
        const int s = (t + 2 < (NTK)) ? t + 2 : (NTK)-1;                      \
        stA(AGX(s), LDG, As, aby2, wave, srow, csrc);                         \
        stB(BGX(s), LDG, Bs, bby2, wave, srow, csrc);                         \
        LGKM0 SB                                                              \
        __builtin_amdgcn_s_setprio(1);                                        \
        MFMA16                                                                \
        __builtin_amdgcn_s_setprio(0);                                        \
        VMW3;                                                                 \
        BAR;                                                                  \
        unsigned tmp = aby0; aby0 = aby1; aby1 = aby2; aby2 = tmp;            \
        tmp = bby0; bby0 = bby1; bby1 = bby2; bby2 = tmp;                     \
    }

#define KLOOP(AGX, BGX, LDG, NTK)                                             \
    unsigned aby0 = 0, aby1 = 16384, aby2 = 32768;                            \
    unsigned bby0 = 0, bby1 = 8192,  bby2 = 16384;                            \
    stA(AGX(0), LDG, As, 0, wave, srow, csrc);                                \
    stB(BGX(0), LDG, Bs, 0, wave, srow, csrc);                                \
    stA(AGX(1), LDG, As, 16384, wave, srow, csrc);                            \
    stB(BGX(1), LDG, Bs, 8192, wave, srow, csrc);                             \
    VMW3; BAR;                                                                \
    for (int t = 0; t < (NTK); ++t) KBODY(AGX, BGX, LDG, NTK)

// ---------------- GEMM 1: gate_up + GLU epilogue (rw folded in) ------------

__global__ __launch_bounds__(512, 4) void k_gemm_gateup(
    const u16* __restrict__ xb,    // [T][H] bf16
    const u16* __restrict__ wP,    // [E][4096][H] bf16, gate/up 16-col groups
    const float* __restrict__ gub, // [E][2D] fp32 interleaved
    const float* __restrict__ rw,  // [T][E] fp32
    u16* __restrict__ fused)       // [E][T][D] bf16
{
    // grid 2048; XCD k owns n-tiles {4k..4k+3}; t fastest on-XCD.
    const int id = blockIdx.x;
    const int xcd = id & 7;
    const int local = id >> 3;            // 0..255
    const int e = local >> 5;
    const int rem = local & 31;
    const int t0 = (rem & 7) * 256;
    const int n0 = (xcd * 4 + (rem >> 3)) * 128;

    __shared__ u16 As[3 * 256 * 32];      // 48 KB
    __shared__ u16 Bs[3 * 128 * 32];      // 24 KB
    GEMM_SETUP

    const u16* Ab = xb + (size_t)t0 * H_;
    const u16* Bb = wP + ((size_t)e * N2_ + n0) * H_;
#define AG1(kt) (Ab + (kt) * 32)
#define BG1(kt) (Bb + (kt) * 32)

    KLOOP(AG1, BG1, H_, (H_ / 32))
#undef AG1
#undef BG1

    // epilogue: wave's 32 cols = one 32-group: j=0 gate, j=1 up of d.
    const int d = ((n0 + wc) >> 1) + l16;
    const float bg = gub[e * N2_ + 2 * d];
    const float bu = gub[e * N2_ + 2 * d + 1];
    u16* fbase = fused + (size_t)e * T_ * D_;
    UNROLL for (int i = 0; i < 8; i++) {
        UNROLL for (int r = 0; r < 4; r++) {
            const int row = t0 + wr + i * 16 + quad * 4 + r;
            float g = acc[i][0][r] + bg;
            float u = acc[i][1][r] + bu;
            g = fminf(g, 7.0f);
            u = fminf(fmaxf(u, -7.0f), 7.0f);
            float glu = g / (1.0f + __expf(-1.702f * g));
            float f = (u + 1.0f) * glu * rw[row * E_ + e];
            fbase[(size_t)row * D_ + d] = f2bf(f);
        }
    }
}

// ---------------- GEMM 2: down proj, experts-in-K (K=4096) ----------------

__global__ __launch_bounds__(512, 4) void k_gemm_down(
    const u16* __restrict__ fused, // [E][T][D] bf16 (rw-scaled)
    const u16* __restrict__ wdT,   // [E][H][D] bf16
    float* __restrict__ pout)      // [4][T][H] fp32 partials
{
    // grid 512 = 2 blocks/CU; XCD k owns h-tiles {2k,2k+1}; t fastest.
    const int id = blockIdx.x;
    const int xcd = id & 7;
    const int local = id >> 3;           // 0..63
    const int g = local >> 4;            // expert pair
    const int rem = local & 15;
    const int t0 = (rem & 7) * 256;
    const int h0 = (xcd * 2 + (rem >> 3)) * 128;
    const int e0 = g * 2;

    __shared__ u16 As[3 * 256 * 32];
    __shared__ u16 Bs[3 * 128 * 32];
    GEMM_SETUP

#define AG2(kt) (fused + ((size_t)(e0 + ((kt) >> 6)) * T_ + t0) * D_ + ((kt) & 63) * 32)
#define BG2(kt) (wdT + ((size_t)(e0 + ((kt) >> 6)) * H_ + h0) * D_ + ((kt) & 63) * 32)

    KLOOP(AG2, BG2, D_, (2 * (D_ / 32)))
#undef AG2
#undef BG2

    float* po = pout + (size_t)g * T_ * H_;
    UNROLL for (int i = 0; i < 8; i++) {
        UNROLL for (int r = 0; r < 4; r++) {
            const int row = t0 + wr + i * 16 + quad * 4 + r;
            po[(size_t)row * H_ + h0 + wc + l16]      = acc[i][0][r];
            po[(size_t)row * H_ + h0 + wc + 16 + l16] = acc[i][1][r];
        }
    }
}

// out[t][h] = sum_g pout[g] + sum_e rw[t][e] * down_b[e][h]   (float4)
__global__ __launch_bounds__(256) void k_combine(const float4* __restrict__ p,
                                                 const float* __restrict__ rw,
                                                 const float4* __restrict__ db,
                                                 float4* __restrict__ out) {
    int i = blockIdx.x * 256 + threadIdx.x;
    int t = i >> 9;
    int h4 = i & 511;
    const size_t TH4 = (size_t)T_ * H_ / 4;
    float4 s0 = p[i], s1 = p[i + TH4], s2 = p[i + 2 * TH4], s3 = p[i + 3 * TH4];
    float4 a;
    a.x = s0.x + s1.x + s2.x + s3.x;
    a.y = s0.y + s1.y + s2.y + s3.y;
    a.z = s0.z + s1.z + s2.z + s3.z;
    a.w = s0.w + s1.w + s2.w + s3.w;
#pragma unroll
    for (int e = 0; e < E_; e++) {
        float w = rw[t * E_ + e];
        float4 b = db[e * (H_ / 4) + h4];
        a.x += w * b.x; a.y += w * b.y; a.z += w * b.z; a.w += w * b.w;
    }
    out[i] = a;
}

// ---------------- launch ----------------

extern "C" void kernel_launch(void* const* d_in, const int* in_sizes, int n_in,
                              void* d_out, int out_size, void* d_ws, size_t ws_size,
                              hipStream_t stream) {
    const float* x   = (const float*)d_in[0];
    const float* rw  = (const float*)d_in[1];
    const float* guw = (const float*)d_in[2];
    const float* gub = (const float*)d_in[3];
    const float* dww = (const float*)d_in[4];
    const float* dwb = (const float*)d_in[5];
    float* out = (float*)d_out;

    char* ws = (char*)d_ws;
    u16* xb    = (u16*)(ws);                      //   8 MB  [T][H]
    u16* wP    = (u16*)(ws + 8388608);            // 128 MB  [E][4096][H]
    u16* wdT   = (u16*)(ws + 142606336);          //  64 MB  [E][H][D]
    u16* fused = (u16*)(ws + 209715200);          //  64 MB  [E][T][D]
    float* pout = (float*)(ws + 8388608);         // reuses wP (dead after gemm1)

    k_convert_x<<<dim3((T_ * H_) / 4 / 256), 256, 0, stream>>>((const float4*)x, (ushort4*)xb);
    k_tr_gateup<<<dim3(H_ / 64, D_ / 64, E_), 256, 0, stream>>>(guw, wP);
    k_tr_down<<<dim3(D_ / 64, H_ / 64, E_), 256, 0, stream>>>(dww, wdT);
    k_gemm_gateup<<<dim3(2048), 512, 0, stream>>>(xb, wP, gub, rw, fused);
    k_gemm_down<<<dim3(512), 512, 0, stream>>>(fused, wdT, pout);
    k_combine<<<dim3((T_ * H_) / 4 / 256), 256, 0, stream>>>((const float4*)pout, rw, (const float4*)dwb, (float4*)out);
}